// Round 1
// baseline (3348.592 us; speedup 1.0000x reference)
//
#include <hip/hip_runtime.h>
#include <math.h>

// Problem: B=16, L=1024, D_IN=DM=512, H=8, DK=DV=64.
// Pipeline: LN-stats -> 3x (LN+proj GEMM) -> fused attention (scores+softmax+mask+PV+attn write) -> fc GEMM.
// All fp32 (CDNA4 has no fp32 MFMA; this is the correctness baseline for profiling).
// ws usage (floats): stats 98304 | Q 8.39M | K 8.39M | V 8.39M | ctx 8.39M  => ~135 MB total.

namespace {

// ---------------- LayerNorm row stats (mu, rstd) ----------------
__global__ __launch_bounds__(256)
void ln_stats_kernel(const float* __restrict__ q, const float* __restrict__ k,
                     const float* __restrict__ v, float* __restrict__ stats)
{
  const int t = threadIdx.x;
  const int wv = t >> 6, lane = t & 63;
  const int row = blockIdx.x * 4 + wv;        // 16384 rows
  const int which = blockIdx.y;               // 0:q 1:k 2:v
  const float* x = (which == 0) ? q : (which == 1) ? k : v;
  const float* xr = x + (size_t)row * 512;
  const float4 a = *(const float4*)&xr[lane * 8];
  const float4 b = *(const float4*)&xr[lane * 8 + 4];
  float s  = a.x + a.y + a.z + a.w + b.x + b.y + b.z + b.w;
  float s2 = a.x*a.x + a.y*a.y + a.z*a.z + a.w*a.w
           + b.x*b.x + b.y*b.y + b.z*b.z + b.w*b.w;
  #pragma unroll
  for (int off = 32; off > 0; off >>= 1) {
    s  += __shfl_xor(s, off);
    s2 += __shfl_xor(s2, off);
  }
  if (lane == 0) {
    const float mu  = s * (1.0f / 512.0f);
    const float var = s2 * (1.0f / 512.0f) - mu * mu;
    stats[((size_t)which * 16384 + row) * 2 + 0] = mu;
    stats[((size_t)which * 16384 + row) * 2 + 1] = rsqrtf(var + 1e-5f);
  }
}

// ---------------- 128x128 tiled GEMM: C[M,512] = Xn[M,512] @ W[512,512]^T --------
// MODE 0: input rows normalized on the fly ((x-mu)*rstd*g[k]+b[k]); output scattered
//         to (B,H,L,64) layout.  MODE 1: plain input, plain row-major output.
template<int MODE>
__global__ __launch_bounds__(256)
void gemm512_kernel(const float* __restrict__ X, const float* __restrict__ W,
                    const float* __restrict__ stats, const float* __restrict__ gam,
                    const float* __restrict__ bet, float* __restrict__ out)
{
  __shared__ float As[16][132];
  __shared__ float Bs[16][132];
  __shared__ float sMu[128], sRs[128];
  __shared__ float sG[512], sB[512];

  const int t = threadIdx.x;
  const int col0 = blockIdx.x * 128;
  const int row0 = blockIdx.y * 128;
  const int tx = t & 15, ty = t >> 4;

  if (MODE == 0) {
    if (t < 128) {
      sMu[t] = stats[(size_t)(row0 + t) * 2 + 0];
      sRs[t] = stats[(size_t)(row0 + t) * 2 + 1];
    }
    sG[t] = gam[t]; sG[t + 256] = gam[t + 256];
    sB[t] = bet[t]; sB[t + 256] = bet[t + 256];
  }

  float acc[8][8] = {};

  for (int ks = 0; ks < 32; ++ks) {
    const int k0 = ks * 16;
    __syncthreads();   // also covers sMu/sG visibility on the first iteration
    #pragma unroll
    for (int u = 0; u < 2; ++u) {
      const int f = u * 256 + t;          // float4 id 0..511
      const int r = f >> 2;
      const int kc = (f & 3) * 4;
      float4 xa = *(const float4*)&X[(size_t)(row0 + r) * 512 + k0 + kc];
      if (MODE == 0) {
        const float mu = sMu[r], rs = sRs[r];
        xa.x = (xa.x - mu) * rs * sG[k0+kc+0] + sB[k0+kc+0];
        xa.y = (xa.y - mu) * rs * sG[k0+kc+1] + sB[k0+kc+1];
        xa.z = (xa.z - mu) * rs * sG[k0+kc+2] + sB[k0+kc+2];
        xa.w = (xa.w - mu) * rs * sG[k0+kc+3] + sB[k0+kc+3];
      }
      As[kc+0][r] = xa.x; As[kc+1][r] = xa.y; As[kc+2][r] = xa.z; As[kc+3][r] = xa.w;
      const float4 wb = *(const float4*)&W[(size_t)(col0 + r) * 512 + k0 + kc];
      Bs[kc+0][r] = wb.x; Bs[kc+1][r] = wb.y; Bs[kc+2][r] = wb.z; Bs[kc+3][r] = wb.w;
    }
    __syncthreads();
    #pragma unroll
    for (int kk = 0; kk < 16; ++kk) {
      const float4 a0 = *(const float4*)&As[kk][4*ty];
      const float4 a1 = *(const float4*)&As[kk][4*ty + 64];
      const float4 b0 = *(const float4*)&Bs[kk][4*tx];
      const float4 b1 = *(const float4*)&Bs[kk][4*tx + 64];
      const float av[8] = {a0.x,a0.y,a0.z,a0.w,a1.x,a1.y,a1.z,a1.w};
      const float bv[8] = {b0.x,b0.y,b0.z,b0.w,b1.x,b1.y,b1.z,b1.w};
      #pragma unroll
      for (int i = 0; i < 8; ++i)
        #pragma unroll
        for (int j = 0; j < 8; ++j)
          acc[i][j] += av[i] * bv[j];
    }
  }

  #pragma unroll
  for (int i = 0; i < 8; ++i) {
    const int r = row0 + ((i < 4) ? (4*ty + i) : (64 + 4*ty + (i - 4)));
    const float4 c0 = make_float4(acc[i][0], acc[i][1], acc[i][2], acc[i][3]);
    const float4 c1 = make_float4(acc[i][4], acc[i][5], acc[i][6], acc[i][7]);
    if (MODE == 1) {
      *(float4*)&out[(size_t)r * 512 + col0 + 4*tx]      = c0;
      *(float4*)&out[(size_t)r * 512 + col0 + 64 + 4*tx] = c1;
    } else {
      const int bI = r >> 10, l = r & 1023;
      int c = col0 + 4*tx;
      int h = c >> 6, d = c & 63;
      *(float4*)&out[(((size_t)(bI*8 + h)) << 16) + ((size_t)l << 6) + d] = c0;
      c += 64; h = c >> 6; d = c & 63;
      *(float4*)&out[(((size_t)(bI*8 + h)) << 16) + ((size_t)l << 6) + d] = c1;
    }
  }
}

// ---------------- Fused attention ----------------
// Block: 32 q-rows of one (b,h). Scores (x1/8) staged raw in LDS; softmax applies
// combined mask (off-diag AND mask==0), with disallowed entries contributing
// exp(0-M) to Z exactly as the reference does; attn renormalized by Zc + 1e-13*Z.
// The mask bit is carried via -0.0f encoding so the mask is read only once.
__global__ __launch_bounds__(256)
void attn_kernel(const float* __restrict__ Qp, const float* __restrict__ Kp,
                 const float* __restrict__ Vp, const int* __restrict__ mask,
                 float* __restrict__ attn_out, float* __restrict__ ctx)
{
  __shared__ float sQ[32][66];
  __shared__ float sK[64][66];     // K tile, reused for V tile
  __shared__ float sS[32][1026];   // scores -> +/-exp -> attn (in place)

  const int t = threadIdx.x;
  const int q0 = blockIdx.x * 32;
  const int bh = blockIdx.y;       // b*8 + h
  const int b = bh >> 3, h = bh & 7;
  const float* Qg = Qp + ((size_t)bh << 16);
  const float* Kg = Kp + ((size_t)bh << 16);
  const float* Vg = Vp + ((size_t)bh << 16);

  // load Q tile 32x64
  #pragma unroll
  for (int u = 0; u < 2; ++u) {
    const int f = u * 256 + t;
    const int r = f >> 4, c4 = (f & 15) * 4;
    const float4 v4 = *(const float4*)&Qg[((size_t)(q0 + r) << 6) + c4];
    sQ[r][c4+0] = v4.x; sQ[r][c4+1] = v4.y; sQ[r][c4+2] = v4.z; sQ[r][c4+3] = v4.w;
  }

  // ---- QK^T: raw scores * 0.125 into sS ----
  const int qp = t & 15, kq = t >> 4;
  for (int kt = 0; kt < 16; ++kt) {
    __syncthreads();
    #pragma unroll
    for (int u = 0; u < 4; ++u) {
      const int f = u * 256 + t;
      const int r = f >> 4, c4 = (f & 15) * 4;
      const float4 v4 = *(const float4*)&Kg[((size_t)(kt*64 + r) << 6) + c4];
      sK[r][c4+0] = v4.x; sK[r][c4+1] = v4.y; sK[r][c4+2] = v4.z; sK[r][c4+3] = v4.w;
    }
    __syncthreads();
    float acc[2][4] = {};
    #pragma unroll 4
    for (int i2 = 0; i2 < 32; ++i2) {
      const float2 qa0 = *(const float2*)&sQ[2*qp][2*i2];
      const float2 qa1 = *(const float2*)&sQ[2*qp+1][2*i2];
      #pragma unroll
      for (int j = 0; j < 4; ++j) {
        const float2 kb = *(const float2*)&sK[4*kq + j][2*i2];
        acc[0][j] += qa0.x * kb.x + qa0.y * kb.y;
        acc[1][j] += qa1.x * kb.x + qa1.y * kb.y;
      }
    }
    #pragma unroll
    for (int qi = 0; qi < 2; ++qi)
      #pragma unroll
      for (int j = 0; j < 4; ++j)
        sS[2*qp + qi][kt*64 + 4*kq + j] = acc[qi][j] * 0.125f;
  }
  __syncthreads();

  // ---- softmax: one wave owns 8 rows ----
  const int wv = t >> 6, lane = t & 63;
  for (int r8 = 0; r8 < 8; ++r8) {
    const int row = wv * 8 + r8;
    float* srow = sS[row];
    const int grow = q0 + row;
    const int* mrow = mask + ((size_t)b * 1024 + grow) * 1024;
    // pass A: apply combined mask (disallowed -> -0.0f marker), row max
    float mx = -3.0e38f;
    #pragma unroll
    for (int ch = 0; ch < 16; ++ch) {
      const int kk = ch * 64 + lane;
      float vv = srow[kk];
      const bool c = (kk != grow) && (mrow[kk] == 0);
      vv = c ? vv : -0.0f;
      srow[kk] = vv;
      mx = fmaxf(mx, vv);
    }
    #pragma unroll
    for (int off = 32; off > 0; off >>= 1) mx = fmaxf(mx, __shfl_xor(mx, off));
    // pass B: exponentials; Z over ALL entries (ref semantics), Zc over allowed
    float Z = 0.0f, Zc = 0.0f;
    #pragma unroll
    for (int ch = 0; ch < 16; ++ch) {
      const int kk = ch * 64 + lane;
      const float vv = srow[kk];
      const bool c = (__float_as_uint(vv) != 0x80000000u);
      const float e = __expf(vv - mx);    // e > 0 strictly
      Z += e;
      Zc += c ? e : 0.0f;
      srow[kk] = c ? e : -e;              // sign carries the mask bit
    }
    #pragma unroll
    for (int off = 32; off > 0; off >>= 1) { Z += __shfl_xor(Z, off); Zc += __shfl_xor(Zc, off); }
    const float inv = 1.0f / (Zc + 1e-13f * Z);
    float* arow = attn_out + (((size_t)(h * 16 + b) * 1024 + grow) << 10);
    #pragma unroll
    for (int ch = 0; ch < 16; ++ch) {
      const int kk = ch * 64 + lane;
      const float vv = srow[kk];
      const float a = (vv > 0.0f) ? vv * inv : 0.0f;
      srow[kk] = a;
      arow[kk] = a;                        // coalesced 256B per wave store
    }
  }
  __syncthreads();

  // ---- PV: O[32][64] ----
  const int dq = t >> 4;                   // 0..15 -> d = 4*dq..
  float oacc[2][4] = {};
  for (int kt = 0; kt < 16; ++kt) {
    __syncthreads();
    #pragma unroll
    for (int u = 0; u < 4; ++u) {
      const int f = u * 256 + t;
      const int r = f >> 4, c4 = (f & 15) * 4;
      const float4 v4 = *(const float4*)&Vg[((size_t)(kt*64 + r) << 6) + c4];
      sK[r][c4+0] = v4.x; sK[r][c4+1] = v4.y; sK[r][c4+2] = v4.z; sK[r][c4+3] = v4.w;
    }
    __syncthreads();
    #pragma unroll 4
    for (int k2 = 0; k2 < 32; ++k2) {
      const int kk = 2 * k2;
      const int kglob = kt * 64 + kk;
      const float2 a0 = *(const float2*)&sS[2*qp][kglob];
      const float2 a1 = *(const float2*)&sS[2*qp+1][kglob];
      const float2 v0a = *(const float2*)&sK[kk][4*dq];
      const float2 v0b = *(const float2*)&sK[kk][4*dq + 2];
      const float2 v1a = *(const float2*)&sK[kk+1][4*dq];
      const float2 v1b = *(const float2*)&sK[kk+1][4*dq + 2];
      const float vv0[4] = {v0a.x, v0a.y, v0b.x, v0b.y};
      const float vv1[4] = {v1a.x, v1a.y, v1b.x, v1b.y};
      #pragma unroll
      for (int j = 0; j < 4; ++j) {
        oacc[0][j] += a0.x * vv0[j] + a0.y * vv1[j];
        oacc[1][j] += a1.x * vv0[j] + a1.y * vv1[j];
      }
    }
  }
  #pragma unroll
  for (int qi = 0; qi < 2; ++qi)
    #pragma unroll
    for (int j = 0; j < 4; ++j) {
      const int grow = q0 + 2*qp + qi;
      const int d = 4*dq + j;
      ctx[((size_t)b * 1024 + grow) * 512 + h * 64 + d] = oacc[qi][j];
    }
}

} // namespace

extern "C" void kernel_launch(void* const* d_in, const int* in_sizes, int n_in,
                              void* d_out, int out_size, void* d_ws, size_t ws_size,
                              hipStream_t stream)
{
  const float* q   = (const float*)d_in[0];
  const float* k   = (const float*)d_in[1];
  const float* v   = (const float*)d_in[2];
  const int*  mask = (const int*)  d_in[3];
  const float* Wq  = (const float*)d_in[4];
  const float* Wk  = (const float*)d_in[5];
  const float* Wv  = (const float*)d_in[6];
  const float* Wfc = (const float*)d_in[7];
  const float* g1  = (const float*)d_in[8];  const float* b1 = (const float*)d_in[9];
  const float* g2  = (const float*)d_in[10]; const float* b2 = (const float*)d_in[11];
  const float* g3  = (const float*)d_in[12]; const float* b3 = (const float*)d_in[13];

  float* ws    = (float*)d_ws;
  float* stats = ws;                       // 3 * 16384 * 2
  float* Qp    = ws + 98304;               // (B,H,L,64)
  float* Kp    = Qp + 8388608;
  float* Vp    = Kp + 8388608;
  float* ctx   = Vp + 8388608;             // (B,L,512)

  float* dyn  = (float*)d_out;             // (B,L,512)
  float* attn = dyn + 8388608;             // (H*B,L,L)

  hipLaunchKernelGGL(ln_stats_kernel, dim3(4096, 3), dim3(256), 0, stream,
                     q, k, v, stats);
  hipLaunchKernelGGL((gemm512_kernel<0>), dim3(4, 128), dim3(256), 0, stream,
                     q, Wq, stats,         g1, b1, Qp);
  hipLaunchKernelGGL((gemm512_kernel<0>), dim3(4, 128), dim3(256), 0, stream,
                     k, Wk, stats + 32768, g2, b2, Kp);
  hipLaunchKernelGGL((gemm512_kernel<0>), dim3(4, 128), dim3(256), 0, stream,
                     v, Wv, stats + 65536, g3, b3, Vp);
  hipLaunchKernelGGL(attn_kernel, dim3(32, 128), dim3(256), 0, stream,
                     Qp, Kp, Vp, mask, attn, ctx);
  hipLaunchKernelGGL((gemm512_kernel<1>), dim3(4, 128), dim3(256), 0, stream,
                     ctx, Wfc, nullptr, nullptr, nullptr, dyn);
}

// Round 2
// 975.227 us; speedup vs baseline: 3.4337x; 3.4337x over previous
//
#include <hip/hip_runtime.h>
#include <math.h>

// B=16, L=1024, D=DM=512, H=8, DK=DV=64.
// Pipeline (all MFMA bf16; split-bf16 hi/lo on score path):
//   w_split -> mask_bits -> 3x(ln_split -> proj GEMM) -> fused attn (2-pass, no score staging) -> fc GEMM.
// ws layout (bytes):
//   Wq_h 0 | Wq_l 512K | Wk_h 1M | Wk_l 1.5M | Wv_h 2M | Wfc_h 2.5M | bits 3M(2MB)
//   Qh 5242880 | Ql | Kh | Kl | Vt (5 x 16MB) | Xh 89128960 | Xl 105906176  (peak ~117MB)
//   ctx aliases Xh after V-proj is done.

namespace {

typedef __attribute__((ext_vector_type(8))) short bf16x8;
typedef __attribute__((ext_vector_type(4))) float f32x4;
typedef __attribute__((ext_vector_type(4))) unsigned int u32x4;
typedef __attribute__((ext_vector_type(8))) unsigned short u16x8;
typedef unsigned short u16;
typedef unsigned int u32;
typedef unsigned long long u64;

#define MFMA16(a, b, c) __builtin_amdgcn_mfma_f32_16x16x32_bf16((a), (b), (c), 0, 0, 0)

__device__ __forceinline__ u16 f2bf(float x) {
  u32 u = __float_as_uint(x);
  u32 r = u + 0x7FFFu + ((u >> 16) & 1u);
  return (u16)(r >> 16);
}
__device__ __forceinline__ float bf2f(u16 h) { return __uint_as_float(((u32)h) << 16); }

// ---------------- fused LayerNorm + bf16 hi/lo split (one wave per row) -------------
__global__ __launch_bounds__(256)
void ln_split_kernel(const float* __restrict__ x, const float* __restrict__ g,
                     const float* __restrict__ bb, u16* __restrict__ hi,
                     u16* __restrict__ lo, int writeLo)
{
  const int t = threadIdx.x, wid = t >> 6, lane = t & 63;
  const int row = blockIdx.x * 4 + wid;
  const float* xr = x + (size_t)row * 512;
  const int c0 = lane * 8;
  const float4 a = *(const float4*)&xr[c0];
  const float4 b4 = *(const float4*)&xr[c0 + 4];
  float s = a.x + a.y + a.z + a.w + b4.x + b4.y + b4.z + b4.w;
  float s2 = a.x*a.x + a.y*a.y + a.z*a.z + a.w*a.w + b4.x*b4.x + b4.y*b4.y + b4.z*b4.z + b4.w*b4.w;
  #pragma unroll
  for (int off = 32; off; off >>= 1) { s += __shfl_xor(s, off); s2 += __shfl_xor(s2, off); }
  const float mu = s * (1.f / 512.f);
  const float rs = rsqrtf(s2 * (1.f / 512.f) - mu * mu + 1e-5f);
  const float4 ga = *(const float4*)&g[c0], gb = *(const float4*)&g[c0 + 4];
  const float4 ba = *(const float4*)&bb[c0], bz = *(const float4*)&bb[c0 + 4];
  const float xv[8] = {a.x, a.y, a.z, a.w, b4.x, b4.y, b4.z, b4.w};
  const float gg[8] = {ga.x, ga.y, ga.z, ga.w, gb.x, gb.y, gb.z, gb.w};
  const float bv[8] = {ba.x, ba.y, ba.z, ba.w, bz.x, bz.y, bz.z, bz.w};
  u16x8 hv, lv;
  #pragma unroll
  for (int i = 0; i < 8; ++i) {
    const float xn = (xv[i] - mu) * rs * gg[i] + bv[i];
    const u16 h = f2bf(xn);
    hv[i] = h;
    lv[i] = f2bf(xn - bf2f(h));
  }
  *(u16x8*)&hi[(size_t)row * 512 + c0] = hv;
  if (writeLo) *(u16x8*)&lo[(size_t)row * 512 + c0] = lv;
}

// ---------------- weight bf16 hi/lo split (4 weights of 512x512) -------------------
__global__ __launch_bounds__(256)
void w_split_kernel(const float* __restrict__ w0, const float* __restrict__ w1,
                    const float* __restrict__ w2, const float* __restrict__ w3,
                    u16* __restrict__ h0, u16* __restrict__ h1,
                    u16* __restrict__ h2, u16* __restrict__ h3,
                    u16* __restrict__ l0, u16* __restrict__ l1)
{
  const int wsel = blockIdx.y;
  const float* src = wsel == 0 ? w0 : wsel == 1 ? w1 : wsel == 2 ? w2 : w3;
  u16* hd = wsel == 0 ? h0 : wsel == 1 ? h1 : wsel == 2 ? h2 : h3;
  u16* ld = wsel == 0 ? l0 : wsel == 1 ? l1 : nullptr;
  const size_t base = ((size_t)blockIdx.x * 256 + threadIdx.x) * 8;
  const float4 a = *(const float4*)&src[base];
  const float4 b = *(const float4*)&src[base + 4];
  const float xv[8] = {a.x, a.y, a.z, a.w, b.x, b.y, b.z, b.w};
  u16x8 hv, lv;
  #pragma unroll
  for (int i = 0; i < 8; ++i) {
    const u16 h = f2bf(xv[i]);
    hv[i] = h;
    lv[i] = f2bf(xv[i] - bf2f(h));
  }
  *(u16x8*)&hd[base] = hv;
  if (ld) *(u16x8*)&ld[base] = lv;
}

// ---------------- mask -> bitmask (bit=1 iff mask==0, i.e. allowed-by-mask) --------
__global__ __launch_bounds__(256)
void mask_bits_kernel(const int* __restrict__ mask, u32* __restrict__ bits)
{
  const int t = threadIdx.x, wid = t >> 6, lane = t & 63;
  const int r = blockIdx.x * 4 + wid;             // b*1024 + q
  const int* mrow = mask + (size_t)r * 1024;
  #pragma unroll
  for (int j = 0; j < 16; ++j) {
    const u64 bm = __ballot(mrow[j * 64 + lane] == 0);
    if (lane == 0) {
      bits[(size_t)r * 32 + 2 * j] = (u32)bm;
      bits[(size_t)r * 32 + 2 * j + 1] = (u32)(bm >> 32);
    }
  }
}

// ---------------- MFMA GEMM: C[M][N] = A[M][512] * B[N][512]^T ---------------------
// SPLIT=1: A,B have hi/lo planes (3 MFMA per frag pair). OUT: 0 = scale+split ->
// (b,h,l,d) hi/lo planes; 1 = bf16 row-major (ldc); 2 = fp32 row-major (ldc).
template<int SPLIT, int OUT>
__global__ __launch_bounds__(256)
void gemm_bf16_kernel(const u16* __restrict__ Ah, const u16* __restrict__ Al,
                      const u16* __restrict__ Bh, const u16* __restrict__ Bl,
                      int ldc, float scale, void* __restrict__ out0, void* __restrict__ out1)
{
  __shared__ u16 lds[SPLIT ? 32768 : 16384];
  u16* sA = lds;                 // [128][64] bf16, XOR-swizzled rows of 128B
  u16* sB = lds + 8192;
  u16* sAl = SPLIT ? lds + 16384 : nullptr;
  u16* sBl = SPLIT ? lds + 24576 : nullptr;

  const int t = threadIdx.x, lane = t & 63, wid = t >> 6;
  const int wm = wid >> 1, wn = wid & 1, l15 = lane & 15, l4 = lane >> 4;
  const int row0 = blockIdx.y * 128, col0 = blockIdx.x * 128;

  f32x4 acc[4][4];
  #pragma unroll
  for (int i = 0; i < 4; ++i)
    #pragma unroll
    for (int j = 0; j < 4; ++j) acc[i][j] = (f32x4)0.0f;

  for (int kt = 0; kt < 8; ++kt) {
    const int k0 = kt * 64;
    u32x4 ra[4], rb[4], ral[SPLIT ? 4 : 1], rbl[SPLIT ? 4 : 1];
    #pragma unroll
    for (int j = 0; j < 4; ++j) {
      const int off = j * 4096 + t * 16;
      const int row = off >> 7, colb = off & 127;
      ra[j] = *(const u32x4*)((const char*)Ah + (size_t)(row0 + row) * 1024 + k0 * 2 + colb);
      rb[j] = *(const u32x4*)((const char*)Bh + (size_t)(col0 + row) * 1024 + k0 * 2 + colb);
      if (SPLIT) {
        ral[j] = *(const u32x4*)((const char*)Al + (size_t)(row0 + row) * 1024 + k0 * 2 + colb);
        rbl[j] = *(const u32x4*)((const char*)Bl + (size_t)(col0 + row) * 1024 + k0 * 2 + colb);
      }
    }
    __syncthreads();
    #pragma unroll
    for (int j = 0; j < 4; ++j) {
      const int off = j * 4096 + t * 16;
      const int row = off >> 7, colb = off & 127;
      const int lb = row * 128 + (colb ^ ((row & 7) << 4));
      *(u32x4*)((char*)sA + lb) = ra[j];
      *(u32x4*)((char*)sB + lb) = rb[j];
      if (SPLIT) { *(u32x4*)((char*)sAl + lb) = ral[j]; *(u32x4*)((char*)sBl + lb) = rbl[j]; }
    }
    __syncthreads();
    #pragma unroll
    for (int kc = 0; kc < 2; ++kc) {
      bf16x8 af[4], bfm[4], afl[4], bfl[4];
      #pragma unroll
      for (int i = 0; i < 4; ++i) {
        const int rowA = wm * 64 + i * 16 + l15;
        const int byA = rowA * 128 + (((kc * 64) + l4 * 16) ^ ((rowA & 7) << 4));
        af[i] = *(const bf16x8*)((const char*)sA + byA);
        const int rowB = wn * 64 + i * 16 + l15;
        const int byB = rowB * 128 + (((kc * 64) + l4 * 16) ^ ((rowB & 7) << 4));
        bfm[i] = *(const bf16x8*)((const char*)sB + byB);
        if (SPLIT) {
          afl[i] = *(const bf16x8*)((const char*)sAl + byA);
          bfl[i] = *(const bf16x8*)((const char*)sBl + byB);
        }
      }
      #pragma unroll
      for (int mi = 0; mi < 4; ++mi)
        #pragma unroll
        for (int nj = 0; nj < 4; ++nj) {
          acc[mi][nj] = MFMA16(af[mi], bfm[nj], acc[mi][nj]);
          if (SPLIT) {
            acc[mi][nj] = MFMA16(af[mi], bfl[nj], acc[mi][nj]);
            acc[mi][nj] = MFMA16(afl[mi], bfm[nj], acc[mi][nj]);
          }
        }
    }
  }
  // epilogue  (C layout: col = lane&15, row = (lane>>4)*4 + reg)
  #pragma unroll
  for (int mi = 0; mi < 4; ++mi)
    #pragma unroll
    for (int nj = 0; nj < 4; ++nj)
      #pragma unroll
      for (int r = 0; r < 4; ++r) {
        const int gr = row0 + wm * 64 + mi * 16 + l4 * 4 + r;
        const int gc = col0 + wn * 64 + nj * 16 + l15;
        const float v = acc[mi][nj][r] * scale;
        if (OUT == 2) {
          ((float*)out0)[(size_t)gr * ldc + gc] = v;
        } else if (OUT == 1) {
          ((u16*)out0)[(size_t)gr * ldc + gc] = f2bf(v);
        } else {
          const u16 h = f2bf(v);
          const u16 lo = f2bf(v - bf2f(h));
          const size_t off = (((size_t)((gr >> 10) * 8 + (gc >> 6))) << 16) +
                             ((size_t)(gr & 1023) << 6) + (gc & 63);
          ((u16*)out0)[off] = h;
          ((u16*)out1)[off] = lo;
        }
      }
}

// ---------------- fused attention: 2-pass, MFMA, no score staging ------------------
// Block = 128 q-rows of one (b,h); 4 waves, each owns 32 q-rows x all k.
// Shift-0 softmax (exact shift invariance incl. renorm term):
//   attn[q][k] = allowed ? exp(s)/ (Zc*(1+1e-13) + 1e-13*n_masked) : 0
__global__ __launch_bounds__(256)
void attn_kernel(const u16* __restrict__ Qh, const u16* __restrict__ Ql,
                 const u16* __restrict__ Kh, const u16* __restrict__ Kl,
                 const u16* __restrict__ Vt, const u32* __restrict__ bits,
                 float* __restrict__ attn_out, u16* __restrict__ ctx)
{
  __shared__ u16 sKh[4096], sKl[4096], sV[4096];   // [64][64] bf16, swizzled
  __shared__ u32 sBits[4096];                      // [128 rows][32 words]
  __shared__ float sNm[128];                       // n_masked per row
  __shared__ u16 sP[4][2048];                      // per-wave P tile [32][64], swizzled

  const int t = threadIdx.x, lane = t & 63, wid = t >> 6;
  const int l15 = lane & 15, l4 = lane >> 4;
  const int q0 = blockIdx.x * 128;
  const int bh = blockIdx.y, b = bh >> 3, h = bh & 7;
  const int rbase = wid * 32 + l4 * 4;             // + qi*16 + r -> row-in-block

  { // stage bits for this block's 128 q-rows (16 KB, coalesced)
    const u32x4* src = (const u32x4*)(bits + ((size_t)(b << 10) + q0) * 32);
    u32x4* dst = (u32x4*)sBits;
    #pragma unroll
    for (int j = 0; j < 4; ++j) dst[j * 256 + t] = src[j * 256 + t];
  }
  __syncthreads();
  if (t < 128) {
    int pop = 0;
    #pragma unroll
    for (int w = 0; w < 32; ++w) pop += __popc(sBits[t * 32 + w]);
    const int qg = q0 + t;
    const int self = (sBits[t * 32 + (qg >> 5)] >> (qg & 31)) & 1;
    sNm[t] = (float)(1024 - pop + self);           // diag always masked
  }

  // Q fragments (held in registers for both passes)
  const char* Qhb = (const char*)(Qh + ((size_t)bh << 16));
  const char* Qlb = (const char*)(Ql + ((size_t)bh << 16));
  bf16x8 qh[2][2], qlo[2][2];
  #pragma unroll
  for (int qi = 0; qi < 2; ++qi)
    #pragma unroll
    for (int kc = 0; kc < 2; ++kc) {
      const size_t byo = (size_t)(q0 + wid * 32 + qi * 16 + l15) * 128 + kc * 64 + l4 * 16;
      qh[qi][kc] = *(const bf16x8*)(Qhb + byo);
      qlo[qi][kc] = *(const bf16x8*)(Qlb + byo);
    }

  const char* Khb = (const char*)(Kh + ((size_t)bh << 16));
  const char* Klb = (const char*)(Kl + ((size_t)bh << 16));
  const char* Vtb = (const char*)(Vt + (size_t)(h * 64) * 16384 + ((size_t)b << 10));

  float Zc[2][4];
  #pragma unroll
  for (int qi = 0; qi < 2; ++qi)
    #pragma unroll
    for (int r = 0; r < 4; ++r) Zc[qi][r] = 0.f;

  // ---------------- pass 1: accumulate Zc ----------------
  for (int kt = 0; kt < 16; ++kt) {
    const int k0 = kt * 64;
    u32x4 rkh[2], rkl[2];
    #pragma unroll
    for (int j = 0; j < 2; ++j) {
      const int off = j * 4096 + t * 16;
      const int row = off >> 7, colb = off & 127;
      rkh[j] = *(const u32x4*)(Khb + (size_t)(k0 + row) * 128 + colb);
      rkl[j] = *(const u32x4*)(Klb + (size_t)(k0 + row) * 128 + colb);
    }
    __syncthreads();
    #pragma unroll
    for (int j = 0; j < 2; ++j) {
      const int off = j * 4096 + t * 16;
      const int row = off >> 7, colb = off & 127;
      const int lb = row * 128 + (colb ^ ((row & 7) << 4));
      *(u32x4*)((char*)sKh + lb) = rkh[j];
      *(u32x4*)((char*)sKl + lb) = rkl[j];
    }
    __syncthreads();
    u64 W[2][4];
    #pragma unroll
    for (int qi = 0; qi < 2; ++qi)
      #pragma unroll
      for (int r = 0; r < 4; ++r)
        W[qi][r] = *(const u64*)&sBits[(rbase + qi * 16 + r) * 32 + kt * 2];
    #pragma unroll
    for (int ki = 0; ki < 4; ++ki) {
      bf16x8 kb[2], kbl[2];
      #pragma unroll
      for (int kc = 0; kc < 2; ++kc) {
        const int rowK = ki * 16 + l15;
        const int by = rowK * 128 + (((kc * 64) + l4 * 16) ^ ((rowK & 7) << 4));
        kb[kc] = *(const bf16x8*)((const char*)sKh + by);
        kbl[kc] = *(const bf16x8*)((const char*)sKl + by);
      }
      const int colr = ki * 16 + l15;
      #pragma unroll
      for (int qi = 0; qi < 2; ++qi) {
        f32x4 a = (f32x4)0.0f;
        #pragma unroll
        for (int kc = 0; kc < 2; ++kc) {
          a = MFMA16(qh[qi][kc], kb[kc], a);
          a = MFMA16(qh[qi][kc], kbl[kc], a);
          a = MFMA16(qlo[qi][kc], kb[kc], a);
        }
        #pragma unroll
        for (int r = 0; r < 4; ++r) {
          const int rloc = rbase + qi * 16 + r;
          const bool allowed = (((W[qi][r] >> colr) & 1ull) != 0) && ((k0 + colr) != (q0 + rloc));
          const float e = __expf(a[r]);
          Zc[qi][r] += allowed ? e : 0.f;
        }
      }
    }
  }
  // cross-lane combine (16-lane groups own full rows) + denominator
  float inv[2][4];
  #pragma unroll
  for (int qi = 0; qi < 2; ++qi)
    #pragma unroll
    for (int r = 0; r < 4; ++r) {
      float z = Zc[qi][r];
      z += __shfl_xor(z, 1); z += __shfl_xor(z, 2);
      z += __shfl_xor(z, 4); z += __shfl_xor(z, 8);
      const float nm = sNm[rbase + qi * 16 + r];
      inv[qi][r] = 1.0f / (z * (1.0f + 1e-13f) + 1e-13f * nm);
    }

  // ---------------- pass 2: attn write + PV ----------------
  f32x4 ctxa[2][4];
  #pragma unroll
  for (int qi = 0; qi < 2; ++qi)
    #pragma unroll
    for (int dj = 0; dj < 4; ++dj) ctxa[qi][dj] = (f32x4)0.0f;

  u16* sPw = sP[wid];
  float* aout = attn_out + (((size_t)(h * 16 + b)) << 20);

  for (int kt = 0; kt < 16; ++kt) {
    const int k0 = kt * 64;
    u32x4 rkh[2], rkl[2], rv[2];
    #pragma unroll
    for (int j = 0; j < 2; ++j) {
      const int off = j * 4096 + t * 16;
      const int row = off >> 7, colb = off & 127;
      rkh[j] = *(const u32x4*)(Khb + (size_t)(k0 + row) * 128 + colb);
      rkl[j] = *(const u32x4*)(Klb + (size_t)(k0 + row) * 128 + colb);
      rv[j] = *(const u32x4*)(Vtb + (size_t)row * 32768 + (size_t)k0 * 2 + colb);
    }
    __syncthreads();
    #pragma unroll
    for (int j = 0; j < 2; ++j) {
      const int off = j * 4096 + t * 16;
      const int row = off >> 7, colb = off & 127;
      const int lb = row * 128 + (colb ^ ((row & 7) << 4));
      *(u32x4*)((char*)sKh + lb) = rkh[j];
      *(u32x4*)((char*)sKl + lb) = rkl[j];
      *(u32x4*)((char*)sV + lb) = rv[j];
    }
    __syncthreads();
    u64 W[2][4];
    #pragma unroll
    for (int qi = 0; qi < 2; ++qi)
      #pragma unroll
      for (int r = 0; r < 4; ++r)
        W[qi][r] = *(const u64*)&sBits[(rbase + qi * 16 + r) * 32 + kt * 2];
    #pragma unroll
    for (int ki = 0; ki < 4; ++ki) {
      bf16x8 kb[2], kbl[2];
      #pragma unroll
      for (int kc = 0; kc < 2; ++kc) {
        const int rowK = ki * 16 + l15;
        const int by = rowK * 128 + (((kc * 64) + l4 * 16) ^ ((rowK & 7) << 4));
        kb[kc] = *(const bf16x8*)((const char*)sKh + by);
        kbl[kc] = *(const bf16x8*)((const char*)sKl + by);
      }
      const int colr = ki * 16 + l15;
      #pragma unroll
      for (int qi = 0; qi < 2; ++qi) {
        f32x4 a = (f32x4)0.0f;
        #pragma unroll
        for (int kc = 0; kc < 2; ++kc) {
          a = MFMA16(qh[qi][kc], kb[kc], a);
          a = MFMA16(qh[qi][kc], kbl[kc], a);
          a = MFMA16(qlo[qi][kc], kb[kc], a);
        }
        #pragma unroll
        for (int r = 0; r < 4; ++r) {
          const int rloc = rbase + qi * 16 + r;
          const bool allowed = (((W[qi][r] >> colr) & 1ull) != 0) && ((k0 + colr) != (q0 + rloc));
          const float p = allowed ? __expf(a[r]) * inv[qi][r] : 0.0f;
          aout[((size_t)(q0 + rloc) << 10) + k0 + colr] = p;
          const int lp = qi * 16 + l4 * 4 + r;
          const int lby = lp * 128 + ((colr * 2) ^ ((lp & 7) << 4));
          *(u16*)((char*)sPw + lby) = f2bf(p);
        }
      }
    }
    // PV: ctx[32q][64d] += P[32q][64k] * V[64k][64d]   (V staged transposed: sV[d][k])
    bf16x8 pA[2][2];
    #pragma unroll
    for (int qi = 0; qi < 2; ++qi)
      #pragma unroll
      for (int kc = 0; kc < 2; ++kc) {
        const int rowP = qi * 16 + l15;
        const int by = rowP * 128 + (((kc * 64) + l4 * 16) ^ ((rowP & 7) << 4));
        pA[qi][kc] = *(const bf16x8*)((const char*)sPw + by);
      }
    #pragma unroll
    for (int dj = 0; dj < 4; ++dj) {
      bf16x8 vB[2];
      #pragma unroll
      for (int kc = 0; kc < 2; ++kc) {
        const int rowV = dj * 16 + l15;
        const int by = rowV * 128 + (((kc * 64) + l4 * 16) ^ ((rowV & 7) << 4));
        vB[kc] = *(const bf16x8*)((const char*)sV + by);
      }
      #pragma unroll
      for (int qi = 0; qi < 2; ++qi) {
        ctxa[qi][dj] = MFMA16(pA[qi][0], vB[0], ctxa[qi][dj]);
        ctxa[qi][dj] = MFMA16(pA[qi][1], vB[1], ctxa[qi][dj]);
      }
    }
  }
  // ctx epilogue: [b*1024+q][512] bf16, head-concat layout
  #pragma unroll
  for (int qi = 0; qi < 2; ++qi)
    #pragma unroll
    for (int dj = 0; dj < 4; ++dj)
      #pragma unroll
      for (int r = 0; r < 4; ++r) {
        const int gq = q0 + rbase + qi * 16 + r;
        const int gd = h * 64 + dj * 16 + l15;
        ctx[((size_t)(b << 10) + gq) * 512 + gd] = f2bf(ctxa[qi][dj][r]);
      }
}

} // namespace

extern "C" void kernel_launch(void* const* d_in, const int* in_sizes, int n_in,
                              void* d_out, int out_size, void* d_ws, size_t ws_size,
                              hipStream_t stream)
{
  const float* q = (const float*)d_in[0];
  const float* k = (const float*)d_in[1];
  const float* v = (const float*)d_in[2];
  const int* mask = (const int*)d_in[3];
  const float* Wq = (const float*)d_in[4];
  const float* Wk = (const float*)d_in[5];
  const float* Wv = (const float*)d_in[6];
  const float* Wfc = (const float*)d_in[7];
  const float* g1 = (const float*)d_in[8];  const float* b1 = (const float*)d_in[9];
  const float* g2 = (const float*)d_in[10]; const float* b2 = (const float*)d_in[11];
  const float* g3 = (const float*)d_in[12]; const float* b3 = (const float*)d_in[13];

  char* ws = (char*)d_ws;
  u16* Wq_h = (u16*)(ws + 0);
  u16* Wq_l = (u16*)(ws + 524288);
  u16* Wk_h = (u16*)(ws + 1048576);
  u16* Wk_l = (u16*)(ws + 1572864);
  u16* Wv_h = (u16*)(ws + 2097152);
  u16* Wfc_h = (u16*)(ws + 2621440);
  u32* bits = (u32*)(ws + 3145728);
  u16* Qh = (u16*)(ws + 5242880);
  u16* Ql = (u16*)(ws + 22020096);
  u16* Kh = (u16*)(ws + 38797312);
  u16* Kl = (u16*)(ws + 55574528);
  u16* Vt = (u16*)(ws + 72351744);
  u16* Xh = (u16*)(ws + 89128960);
  u16* Xl = (u16*)(ws + 105906176);
  u16* ctx = Xh;  // reused after V projection is complete

  float* dyn = (float*)d_out;                 // (B,L,512)
  float* attn = dyn + 8388608;                // (H*B,L,L)

  hipLaunchKernelGGL(w_split_kernel, dim3(128, 4), dim3(256), 0, stream,
                     Wq, Wk, Wv, Wfc, Wq_h, Wk_h, Wv_h, Wfc_h, Wq_l, Wk_l);
  hipLaunchKernelGGL(mask_bits_kernel, dim3(4096), dim3(256), 0, stream, mask, bits);

  hipLaunchKernelGGL(ln_split_kernel, dim3(4096), dim3(256), 0, stream, q, g1, b1, Xh, Xl, 1);
  hipLaunchKernelGGL((gemm_bf16_kernel<1, 0>), dim3(4, 128), dim3(256), 0, stream,
                     Xh, Xl, Wq_h, Wq_l, 0, 0.125f, Qh, Ql);

  hipLaunchKernelGGL(ln_split_kernel, dim3(4096), dim3(256), 0, stream, k, g2, b2, Xh, Xl, 1);
  hipLaunchKernelGGL((gemm_bf16_kernel<1, 0>), dim3(4, 128), dim3(256), 0, stream,
                     Xh, Xl, Wk_h, Wk_l, 0, 1.0f, Kh, Kl);

  hipLaunchKernelGGL(ln_split_kernel, dim3(4096), dim3(256), 0, stream, v, g3, b3, Xh, nullptr, 0);
  hipLaunchKernelGGL((gemm_bf16_kernel<0, 1>), dim3(128, 4), dim3(256), 0, stream,
                     Wv_h, nullptr, Xh, nullptr, 16384, 1.0f, Vt, nullptr);

  hipLaunchKernelGGL(attn_kernel, dim3(8, 128), dim3(256), 0, stream,
                     Qh, Ql, Kh, Kl, Vt, bits, attn, ctx);

  hipLaunchKernelGGL((gemm_bf16_kernel<0, 2>), dim3(4, 128), dim3(256), 0, stream,
                     ctx, nullptr, Wfc_h, nullptr, 512, 1.0f, dyn, nullptr);
}